// Round 12
// baseline (218.454 us; speedup 1.0000x reference)
//
#include <hip/hip_runtime.h>
#include <math.h>

#define NNODES  100000
#define NEDGES  3200000
#define NGRAPHS 1024
#define BNODES  196                              // nodes per bucket
#define NBUCK   ((NNODES + BNODES - 1) / BNODES) // 511
#define SCAP    8192                             // staging capacity per bucket (max ~6.6K)
#define PADCAP  12288                            // padded-32 entries capacity per bucket
#define SLDS    7168                             // binB LDS staging (max bucket ~6.6K)
#define DUMMY   NNODES                           // dummy node with zero feature rows
#define CHUNK   8192                             // edges per binA block (512 thr x 16)
#define NCHUNKS ((NEDGES + CHUNK - 1) / CHUNK)   // 391

typedef int iv4 __attribute__((ext_vector_type(4)));
typedef float fv2 __attribute__((ext_vector_type(2)));

#if defined(__has_builtin)
#if __has_builtin(__builtin_amdgcn_cvt_pk_f32_fp8) && __has_builtin(__builtin_amdgcn_cvt_pk_fp8_f32)
#define HW_FP8 1
#endif
#endif

// ---- bf16x2 pack/unpack (RNE) ----
__device__ __forceinline__ unsigned bf16pair(float a, float b) {
    unsigned ua = __float_as_uint(a), ub = __float_as_uint(b);
    ua += 0x7fffu + ((ua >> 16) & 1u);
    ub += 0x7fffu + ((ub >> 16) & 1u);
    return (ua >> 16) | (ub & 0xffff0000u);
}
__device__ __forceinline__ float bflo(unsigned u) { return __uint_as_float(u << 16); }
__device__ __forceinline__ float bfhi(unsigned u) { return __uint_as_float(u & 0xffff0000u); }

// ---- fp8 e4m3 (OCP) manual fallback ----
__device__ __forceinline__ unsigned fp8_of(float v) {
    unsigned s = (__float_as_uint(v) >> 24) & 0x80u;
    float a = fminf(fabsf(v), 448.f);
    unsigned ub = __float_as_uint(a);
    unsigned lsb = (ub >> 20) & 1u;
    ub += 0x0007FFFFu + lsb;
    int em = (int)(ub >> 20) - (120 << 3);
    if (em < 1) return s;
    if (em > 0x7E) em = 0x7E;
    return s | (unsigned)em;
}
__device__ __forceinline__ float fp8_to_f(unsigned b) {
    unsigned em = b & 0x7Fu;
    unsigned s = (b & 0x80u) << 24;
    float f = __uint_as_float(s | ((em + 0x3C0u) << 20));
    return (em >= 8u) ? f : 0.f;
}
__device__ __forceinline__ unsigned fp8x4_pack(float a, float b, float c, float d) {
    a = fminf(fmaxf(a, -448.f), 448.f);
    b = fminf(fmaxf(b, -448.f), 448.f);
    c = fminf(fmaxf(c, -448.f), 448.f);
    d = fminf(fmaxf(d, -448.f), 448.f);
#ifdef HW_FP8
    int w = __builtin_amdgcn_cvt_pk_fp8_f32(a, b, 0, false);
    w = __builtin_amdgcn_cvt_pk_fp8_f32(c, d, w, true);
    return (unsigned)w;
#else
    return fp8_of(a) | (fp8_of(b) << 8) | (fp8_of(c) << 16) | (fp8_of(d) << 24);
#endif
}
__device__ __forceinline__ fv2 f8lo(unsigned w) {
#ifdef HW_FP8
    return __builtin_amdgcn_cvt_pk_f32_fp8((int)w, false);
#else
    fv2 t; t.x = fp8_to_f(w & 0xFFu); t.y = fp8_to_f((w >> 8) & 0xFFu); return t;
#endif
}
__device__ __forceinline__ fv2 f8hi(unsigned w) {
#ifdef HW_FP8
    return __builtin_amdgcn_cvt_pk_f32_fp8((int)w, true);
#else
    fv2 t; t.x = fp8_to_f((w >> 16) & 0xFFu); t.y = fp8_to_f(w >> 24); return t;
#endif
}

// ---------------- init ----------------

__global__ void zero4_kernel(int4* p, int nvec) {
    int i = blockIdx.x * blockDim.x + threadIdx.x;
    if (i < nvec) p[i] = make_int4(0, 0, 0, 0);
}

// ---------------- binA: LDS-staged bucket sort (512 thr, 8K chunk, no bof: 38KB LDS) ----------------

__global__ void __launch_bounds__(512) binA_kernel(const int* __restrict__ src,
        const int* __restrict__ dst, int* __restrict__ bucketCur, int* __restrict__ stage) {
    __shared__ int lcnt[512];
    __shared__ int boff[512];                     // monotone; boff[511] = cnt (sentinel)
    __shared__ int gbase[512];
    __shared__ int cur[512];
    __shared__ int wtot[8];
    __shared__ int packed[CHUNK];                 // 32 KB
    int tid = threadIdx.x;
    int beg = blockIdx.x * CHUNK;
    int end = beg + CHUNK; if (end > NEDGES) end = NEDGES;
    int cnt = end - beg;

    lcnt[tid] = 0;
    __syncthreads();

    int ent[16];
    int bk[16];
#pragma unroll
    for (int it = 0; it < 4; ++it) {
        int e0 = beg + tid * 4 + it * 2048;
        if (e0 < end) {
            iv4 d4 = __builtin_nontemporal_load((const iv4*)(dst + e0));
            iv4 s4 = __builtin_nontemporal_load((const iv4*)(src + e0));
            int b;
            b = d4.x / BNODES; ent[it*4+0] = s4.x | ((d4.x - b*BNODES) << 17); bk[it*4+0] = b; atomicAdd(&lcnt[b], 1);
            b = d4.y / BNODES; ent[it*4+1] = s4.y | ((d4.y - b*BNODES) << 17); bk[it*4+1] = b; atomicAdd(&lcnt[b], 1);
            b = d4.z / BNODES; ent[it*4+2] = s4.z | ((d4.z - b*BNODES) << 17); bk[it*4+2] = b; atomicAdd(&lcnt[b], 1);
            b = d4.w / BNODES; ent[it*4+3] = s4.w | ((d4.w - b*BNODES) << 17); bk[it*4+3] = b; atomicAdd(&lcnt[b], 1);
        } else {
            bk[it*4+0] = -1; bk[it*4+1] = -1; bk[it*4+2] = -1; bk[it*4+3] = -1;
            ent[it*4+0] = 0; ent[it*4+1] = 0; ent[it*4+2] = 0; ent[it*4+3] = 0;
        }
    }
    __syncthreads();

    // wave-level scan, 1 bucket per thread (512 threads >= NBUCK+1)
    int c = lcnt[tid];
    int lane = tid & 63, wid = tid >> 6;
    int v = c;
#pragma unroll
    for (int o = 1; o < 64; o <<= 1) {
        int t = __shfl_up(v, o, 64);
        if (lane >= o) v += t;
    }
    if (lane == 63) wtot[wid] = v;
    __syncthreads();
    int woff = 0;
#pragma unroll
    for (int w = 0; w < 8; ++w) woff += (w < wid) ? wtot[w] : 0;
    int excl = woff + v - c;
    boff[tid] = excl;
    cur[tid] = excl;
    if (c > 0) gbase[tid] = atomicAdd(&bucketCur[tid], c);
    __syncthreads();

#pragma unroll
    for (int k = 0; k < 16; ++k) {
        int b = bk[k];
        if (b >= 0) {
            int p = atomicAdd(&cur[b], 1);
            packed[p] = ent[k];
        }
    }
    __syncthreads();

    // ordered copy; bucket of position i via binary search over boff (9 steps)
    for (int i = tid; i < cnt; i += 512) {
        int lo = 0, hi = 511;
        while (lo < hi) {
            int mid = (lo + hi + 1) >> 1;
            if (boff[mid] <= i) lo = mid; else hi = mid - 1;
        }
        int b = lo;
        int addr = b * SCAP + gbase[b] + (i - boff[b]);
        stage[addr] = packed[i];
    }
}

// ---------------- binB: 512 thr, vectorized LDS staging + 32-padded CSR + dinv/xs ----------------

__global__ void __launch_bounds__(512) binB_kernel(const int* __restrict__ bucketCur,
                            const int* __restrict__ stage, const float2* __restrict__ x,
                            int* __restrict__ entries, int* __restrict__ rowptr,
                            int* __restrict__ rowend,
                            float* __restrict__ dinv, unsigned* __restrict__ xs,
                            float* __restrict__ psum_z) {
    __shared__ int s[256];
    __shared__ int ncur[256];
    __shared__ float ndinv[256];
    __shared__ int wt[4];
    __shared__ __align__(16) int se[SLDS];       // 28 KB: whole bucket in LDS
    int b = blockIdx.x;
    int cntE = bucketCur[b];
    if (cntE > SLDS) cntE = SLDS;                // safety (never expected: >11 sigma)
    int bbase = b * PADCAP;
    int nlo = b * BNODES;
    int nn = NNODES - nlo; if (nn > BNODES) nn = BNODES;
    int sb = b * SCAP;
    int tid = threadIdx.x;

    // zero psum+pcnt (contiguous 33792 floats) across the 511 blocks
    {
        int zi = b * 68 + tid;
        if (tid < 68 && zi < 33792) psum_z[zi] = 0.f;
    }

    if (tid < 256) s[tid] = 0;
    __syncthreads();
    int nv4 = cntE >> 2;
    for (int q = tid; q < nv4; q += 512) {
        iv4 w4;
        __builtin_memcpy(&w4, stage + sb + 4 * q, 16);
        __builtin_memcpy(se + 4 * q, &w4, 16);
        atomicAdd(&s[(unsigned)w4.x >> 17], 1);
        atomicAdd(&s[(unsigned)w4.y >> 17], 1);
        atomicAdd(&s[(unsigned)w4.z >> 17], 1);
        atomicAdd(&s[(unsigned)w4.w >> 17], 1);
    }
    {
        int e = (nv4 << 2) + tid;
        if (e < cntE) {
            int w = stage[sb + e];
            se[e] = w;
            atomicAdd(&s[(unsigned)w >> 17], 1);
        }
    }
    __syncthreads();

    int lane = tid & 63, wid = tid >> 6;
    int v = 0, p32 = 0, iv = 0;
    if (tid < 256) {
        v = s[tid];
        p32 = (v + 31) & ~31;            // padded row length (multiple of 32)
        iv = p32;
#pragma unroll
        for (int o = 1; o < 64; o <<= 1) {
            int t = __shfl_up(iv, o, 64);
            if (lane >= o) iv += t;
        }
        if (lane == 63) wt[wid] = iv;
    }
    __syncthreads();
    if (tid < 256) {
        int woff = 0;
#pragma unroll
        for (int w2 = 0; w2 < 4; ++w2) woff += (w2 < wid) ? wt[w2] : 0;
        int pexcl = woff + iv - p32;
        ncur[tid] = pexcl;
        if (tid < nn) {
            rowptr[nlo + tid] = bbase + pexcl;
            rowend[nlo + tid] = bbase + pexcl + p32;
            float di = rsqrtf((float)(v + 1));   // +1 self-loop (exact degree)
            dinv[nlo + tid] = di;
            ndinv[tid] = di;
            // pad fill: slots [v, p32) -> DUMMY
            int base = bbase + pexcl;
            for (int j = v; j < p32; ++j) entries[base + j] = DUMMY;
        }
    }
    __syncthreads();
    for (int i = tid; i < nn * 8; i += 512) {
        int node = i >> 3, w = i & 7;
        float2 v2 = x[(size_t)(nlo + node) * 8 + w];
        float di = ndinv[node];
        xs[(nlo + node) * 8 + w] = bf16pair(v2.x * di, v2.y * di);
    }
    if (b == NBUCK - 1) {
        if (tid < 8) xs[NNODES * 8 + tid] = 0u;  // dummy row = 0
    }
    for (int e = tid; e < cntE; e += 512) {
        unsigned w = (unsigned)se[e];
        int dl = (int)(w >> 17);
        int slot = atomicAdd(&ncur[dl], 1);
        entries[bbase + slot] = (int)(w & 0x1FFFFu);
    }
}

// ---------------- fused gather layer 1 + node MLP (32-edge superblock pipeline) ----------------

__device__ __forceinline__ void acc_bf(unsigned u, fv2& a) {
    fv2 t; t.x = bflo(u); t.y = bfhi(u);
    a += t;
}
#define ACCX4(V) { acc_bf((V).x, acc0); acc_bf((V).y, acc1); acc_bf((V).z, acc2); acc_bf((V).w, acc3); }
#define QRED(a) { a.x += __shfl_xor(a.x, 2); a.y += __shfl_xor(a.y, 2); \
                  a.x += __shfl_xor(a.x, 4); a.y += __shfl_xor(a.y, 4); }

__global__ void __launch_bounds__(256) gatherX_mlp_kernel(const int* __restrict__ entries,
        const int* __restrict__ rowptr, const int* __restrict__ rowend,
        const float* __restrict__ dinv, const uint4* __restrict__ xsv,
        const float* __restrict__ W1, const float* __restrict__ b1,
        const float* __restrict__ W2, unsigned* __restrict__ hm2f) {
    __shared__ __align__(16) float w1s[16 * 64];   // 4 KB
    __shared__ __align__(16) float w2s[64 * 32];   // 8 KB
    __shared__ float bb1[64];
    int tid = threadIdx.x;
    for (int i = tid; i < 16 * 64; i += 256) w1s[i] = W1[i];
    for (int i = tid; i < 64 * 32; i += 256) w2s[i] = W2[i];
    if (tid < 64) bb1[tid] = b1[tid];
    if (blockIdx.x == 0 && tid < 8) hm2f[NNODES * 8 + tid] = 0u;   // dummy row = 0
    __syncthreads();

    int t = blockIdx.x * 256 + tid;
    int n = t >> 3, lane = t & 7;
    int half = lane & 1, quad = lane >> 1;
    int beg = rowptr[n];
    int nb = (rowend[n] - beg) >> 5;         // whole 32-edge superblocks (padded)
    fv2 acc0 = {0.f, 0.f}, acc1 = {0.f, 0.f}, acc2 = {0.f, 0.f}, acc3 = {0.f, 0.f};
    if (quad == 0) {
        uint4 sv = xsv[n * 2 + half];
        ACCX4(sv);
    }

    const int* ep = entries + beg + (quad << 2);
    if (nb > 0) {
        uint4 p0, p1, p2, p3, p4, p5, p6, p7;
        iv4 fA = {0, 0, 0, 0}, fB = {0, 0, 0, 0};
        {
            iv4 eA, eB;
            __builtin_memcpy(&eA, ep, 16);
            __builtin_memcpy(&eB, ep + 16, 16);
            p0 = xsv[eA.x * 2 + half]; p1 = xsv[eA.y * 2 + half];
            p2 = xsv[eA.z * 2 + half]; p3 = xsv[eA.w * 2 + half];
            p4 = xsv[eB.x * 2 + half]; p5 = xsv[eB.y * 2 + half];
            p6 = xsv[eB.z * 2 + half]; p7 = xsv[eB.w * 2 + half];
            if (nb > 1) {
                __builtin_memcpy(&fA, ep + 32, 16);
                __builtin_memcpy(&fB, ep + 48, 16);
            }
        }
        for (int i = 1; i < nb; ++i) {
            uint4 c0 = xsv[fA.x * 2 + half], c1 = xsv[fA.y * 2 + half],
                  c2 = xsv[fA.z * 2 + half], c3 = xsv[fA.w * 2 + half],
                  c4 = xsv[fB.x * 2 + half], c5 = xsv[fB.y * 2 + half],
                  c6 = xsv[fB.z * 2 + half], c7 = xsv[fB.w * 2 + half];
            if (i + 1 < nb) {
                __builtin_memcpy(&fA, ep + ((i + 1) << 5), 16);
                __builtin_memcpy(&fB, ep + ((i + 1) << 5) + 16, 16);
            }
            ACCX4(p0); ACCX4(p1); ACCX4(p2); ACCX4(p3);
            ACCX4(p4); ACCX4(p5); ACCX4(p6); ACCX4(p7);
            p0 = c0; p1 = c1; p2 = c2; p3 = c3;
            p4 = c4; p5 = c5; p6 = c6; p7 = c7;
        }
        ACCX4(p0); ACCX4(p1); ACCX4(p2); ACCX4(p3);
        ACCX4(p4); ACCX4(p5); ACCX4(p6); ACCX4(p7);
    }

    QRED(acc0); QRED(acc1); QRED(acc2); QRED(acc3);

    // all 8 lanes hold the full half-aggregate; scale by dinv
    float di = dinv[n];
    float own[8];
    own[0] = acc0.x * di; own[1] = acc0.y * di; own[2] = acc1.x * di; own[3] = acc1.y * di;
    own[4] = acc2.x * di; own[5] = acc2.y * di; own[6] = acc3.x * di; own[7] = acc3.y * di;
    float oth[8];
#pragma unroll
    for (int i2 = 0; i2 < 8; ++i2) oth[i2] = __shfl_xor(own[i2], 1);
    float a16[16];
#pragma unroll
    for (int k = 0; k < 8; ++k) a16[k]     = (half == 0) ? own[k] : oth[k];
#pragma unroll
    for (int k = 0; k < 8; ++k) a16[8 + k] = (half == 0) ? oth[k] : own[k];

    // phase B: h1[j] for j = lane*8 .. +7 (FMA order preserved)
    float h[8];
    {
        int j0 = lane * 8;
#pragma unroll
        for (int jj = 0; jj < 8; ++jj) h[jj] = bb1[j0 + jj];
#pragma unroll
        for (int k = 0; k < 16; ++k) {
            const float4* wr = (const float4*)(w1s + k * 64 + j0);
            float4 wa = wr[0], wb = wr[1];
            float av = a16[k];
            h[0] += av * wa.x; h[1] += av * wa.y; h[2] += av * wa.z; h[3] += av * wa.w;
            h[4] += av * wb.x; h[5] += av * wb.y; h[6] += av * wb.z; h[7] += av * wb.w;
        }
#pragma unroll
        for (int jj = 0; jj < 8; ++jj) h[jj] = fmaxf(h[jj], 0.f);
    }

    // phase C: h2[j] for j = lane*4 .. +3; h1 via width-8 shuffles, k ascending
    {
        int j0c = lane * 4;
        float c0 = 0.f, c1 = 0.f, c2 = 0.f, c3 = 0.f;
#pragma unroll
        for (int k = 0; k < 64; ++k) {
            float hv = __shfl(h[k & 7], k >> 3, 8);
            float4 w = *(const float4*)(w2s + k * 32 + j0c);
            c0 += hv * w.x; c1 += hv * w.y; c2 += hv * w.z; c3 += hv * w.w;
        }
        float sc = di * 64.f;                       // x64 pre-scale for fp8
        hm2f[n * 8 + lane] = fp8x4_pack(c0 * sc, c1 * sc, c2 * sc, c3 * sc);
    }
}

// ---------------- gather layer 2 + pool: 32-edge superblock pipeline ----------------

#define ACCH4(V) { q0lo += f8lo((V).x); q0hi += f8hi((V).x); \
                   q1lo += f8lo((V).y); q1hi += f8hi((V).y); \
                   q2lo += f8lo((V).z); q2hi += f8hi((V).z); \
                   q3lo += f8lo((V).w); q3hi += f8hi((V).w); }

__global__ void __launch_bounds__(256) gatherH_pool_kernel(const int* __restrict__ entries,
        const int* __restrict__ rowptr, const int* __restrict__ rowend,
        const float* __restrict__ dinv, const uint4* __restrict__ hm4,
        const float4* __restrict__ b2, const int* __restrict__ batch,
        float* __restrict__ psum, float* __restrict__ pcnt) {
    __shared__ float lps[8][32];
    __shared__ float lpc[8];
    int tid = threadIdx.x;
    ((float*)lps)[tid] = 0.f;
    if (tid < 8) lpc[tid] = 0.f;
    __syncthreads();

    int t = blockIdx.x * 256 + tid;
    int n = t >> 3, lane = t & 7;
    int half = lane & 1, quad = lane >> 1;
    int g0 = batch[blockIdx.x * 32];
    int beg = rowptr[n];
    int nb = (rowend[n] - beg) >> 5;
    fv2 q0lo = {0.f,0.f}, q0hi = {0.f,0.f}, q1lo = {0.f,0.f}, q1hi = {0.f,0.f},
        q2lo = {0.f,0.f}, q2hi = {0.f,0.f}, q3lo = {0.f,0.f}, q3hi = {0.f,0.f};
    if (quad == 0) {
        uint4 sv = hm4[n * 2 + half];
        ACCH4(sv);
    }

    const int* ep = entries + beg + (quad << 2);
    if (nb > 0) {
        uint4 p0, p1, p2, p3, p4, p5, p6, p7;
        iv4 fA = {0, 0, 0, 0}, fB = {0, 0, 0, 0};
        {
            iv4 eA, eB;
            __builtin_memcpy(&eA, ep, 16);
            __builtin_memcpy(&eB, ep + 16, 16);
            p0 = hm4[eA.x * 2 + half]; p1 = hm4[eA.y * 2 + half];
            p2 = hm4[eA.z * 2 + half]; p3 = hm4[eA.w * 2 + half];
            p4 = hm4[eB.x * 2 + half]; p5 = hm4[eB.y * 2 + half];
            p6 = hm4[eB.z * 2 + half]; p7 = hm4[eB.w * 2 + half];
            if (nb > 1) {
                __builtin_memcpy(&fA, ep + 32, 16);
                __builtin_memcpy(&fB, ep + 48, 16);
            }
        }
        for (int i = 1; i < nb; ++i) {
            uint4 c0 = hm4[fA.x * 2 + half], c1 = hm4[fA.y * 2 + half],
                  c2 = hm4[fA.z * 2 + half], c3 = hm4[fA.w * 2 + half],
                  c4 = hm4[fB.x * 2 + half], c5 = hm4[fB.y * 2 + half],
                  c6 = hm4[fB.z * 2 + half], c7 = hm4[fB.w * 2 + half];
            if (i + 1 < nb) {
                __builtin_memcpy(&fA, ep + ((i + 1) << 5), 16);
                __builtin_memcpy(&fB, ep + ((i + 1) << 5) + 16, 16);
            }
            ACCH4(p0); ACCH4(p1); ACCH4(p2); ACCH4(p3);
            ACCH4(p4); ACCH4(p5); ACCH4(p6); ACCH4(p7);
            p0 = c0; p1 = c1; p2 = c2; p3 = c3;
            p4 = c4; p5 = c5; p6 = c6; p7 = c7;
        }
        ACCH4(p0); ACCH4(p1); ACCH4(p2); ACCH4(p3);
        ACCH4(p4); ACCH4(p5); ACCH4(p6); ACCH4(p7);
    }

    QRED(q0lo); QRED(q0hi); QRED(q1lo); QRED(q1hi);
    QRED(q2lo); QRED(q2hi); QRED(q3lo); QRED(q3hi);

    if (quad == 0) {
        float sc = dinv[n] * (1.0f / 64.f);         // undo x64 pre-scale
        float4 bv0 = b2[half * 4 + 0], bv1 = b2[half * 4 + 1],
               bv2 = b2[half * 4 + 2], bv3 = b2[half * 4 + 3];
        float vv[16];
        vv[0]  = fmaxf(q0lo.x * sc + bv0.x, 0.f);
        vv[1]  = fmaxf(q0lo.y * sc + bv0.y, 0.f);
        vv[2]  = fmaxf(q0hi.x * sc + bv0.z, 0.f);
        vv[3]  = fmaxf(q0hi.y * sc + bv0.w, 0.f);
        vv[4]  = fmaxf(q1lo.x * sc + bv1.x, 0.f);
        vv[5]  = fmaxf(q1lo.y * sc + bv1.y, 0.f);
        vv[6]  = fmaxf(q1hi.x * sc + bv1.z, 0.f);
        vv[7]  = fmaxf(q1hi.y * sc + bv1.w, 0.f);
        vv[8]  = fmaxf(q2lo.x * sc + bv2.x, 0.f);
        vv[9]  = fmaxf(q2lo.y * sc + bv2.y, 0.f);
        vv[10] = fmaxf(q2hi.x * sc + bv2.z, 0.f);
        vv[11] = fmaxf(q2hi.y * sc + bv2.w, 0.f);
        vv[12] = fmaxf(q3lo.x * sc + bv3.x, 0.f);
        vv[13] = fmaxf(q3lo.y * sc + bv3.y, 0.f);
        vv[14] = fmaxf(q3hi.x * sc + bv3.z, 0.f);
        vv[15] = fmaxf(q3hi.y * sc + bv3.w, 0.f);

        int g = batch[n], gr = g - g0;
        if (gr < 8) {
            float* pg = &lps[gr][half * 16];
#pragma unroll
            for (int k2 = 0; k2 < 16; ++k2) atomicAdd(pg + k2, vv[k2]);
            if (lane == 0) atomicAdd(&lpc[gr], 1.0f);
        } else {
            float* pg = psum + g * 32 + half * 16;
#pragma unroll
            for (int k2 = 0; k2 < 16; ++k2) atomicAdd(pg + k2, vv[k2]);
            if (lane == 0) atomicAdd(&pcnt[g], 1.0f);
        }
    }
    __syncthreads();
    int grf = tid >> 5, f = tid & 31;
    float v = lps[grf][f];
    if (v != 0.f) atomicAdd(&psum[(g0 + grf) * 32 + f], v);
    if (f == 0) {
        float c = lpc[grf];
        if (c != 0.f) atomicAdd(&pcnt[g0 + grf], c);
    }
}

// ---------------- head ----------------

__global__ void head_kernel(const float* __restrict__ psum, const float* __restrict__ pcnt,
                            const float* __restrict__ fc1W, const float* __restrict__ fc1b,
                            const float* __restrict__ fc2W, const float* __restrict__ fc2b,
                            float* __restrict__ out) {
    int g = blockIdx.x * blockDim.x + threadIdx.x;
    if (g >= NGRAPHS) return;
    float inv = 1.0f / fmaxf(pcnt[g], 1.0f);
    float gv[32];
#pragma unroll
    for (int k = 0; k < 32; ++k) gv[k] = psum[g * 32 + k] * inv;
    float o = fc2b[0];
#pragma unroll
    for (int j = 0; j < 16; ++j) {
        float h = fc1b[j];
#pragma unroll
        for (int k = 0; k < 32; ++k) h += gv[k] * fc1W[k * 16 + j];
        h = fmaxf(h, 0.f);
        o += h * fc2W[j];
    }
    out[g] = 1.0f / (1.0f + expf(-o));
}

// ---------------- launch ----------------

extern "C" void kernel_launch(void* const* d_in, const int* in_sizes, int n_in,
                              void* d_out, int out_size, void* d_ws, size_t ws_size,
                              hipStream_t stream) {
    const float* x    = (const float*)d_in[0];
    const int*   ei   = (const int*)d_in[1];
    const int*   batch= (const int*)d_in[2];
    const float* W1   = (const float*)d_in[3];
    const float* b1   = (const float*)d_in[4];
    const float* W2   = (const float*)d_in[5];
    const float* b2   = (const float*)d_in[6];
    const float* fc1W = (const float*)d_in[7];
    const float* fc1b = (const float*)d_in[8];
    const float* fc2W = (const float*)d_in[9];
    const float* fc2b = (const float*)d_in[10];
    float* out = (float*)d_out;

    const int* src = ei;
    const int* dst = ei + NEDGES;

    char* wsb = (char*)d_ws;
    int*      bucketCur = (int*)wsb;                 // 2048 B  (zeroed by zero4)
    float*    psum      = (float*)(wsb + 2048);      // 131072  (zeroed in binB)
    float*    pcnt      = (float*)(wsb + 133120);    // 4096    (zeroed in binB)
    float*    dinv      = (float*)(wsb + 137216);    // 400000
    int*      rowptr    = (int*)(wsb + 537216);      // 400000
    int*      rowend    = (int*)(wsb + 937216);      // 400000
    int*      stage     = (int*)(wsb + 1337216);     // 16.7 MB (511*8192*4)
    int*      entries   = (int*)(wsb + 18081664);    // 25.1 MB (511*12288*4, 32-padded CSR)
    unsigned* xs        = (unsigned*)(wsb + 43198336);   // 3.2 MB + dummy row (bf16x2)
    unsigned* hm2f      = (unsigned*)(wsb + 46398368);   // 3.2 MB + dummy row (fp8)

    const int B = 256;
    zero4_kernel<<<1, 128, 0, stream>>>((int4*)wsb, 128);   // bucketCur only

    binA_kernel<<<NCHUNKS, 512, 0, stream>>>(src, dst, bucketCur, stage);
    binB_kernel<<<NBUCK, 512, 0, stream>>>(bucketCur, stage, (const float2*)x,
                                           entries, rowptr, rowend, dinv, xs, psum);

    const int GTH = NNODES * 8 / B;                  // 3125
    gatherX_mlp_kernel<<<GTH, B, 0, stream>>>(entries, rowptr, rowend, dinv,
                                              (const uint4*)xs, W1, b1, W2, hm2f);
    gatherH_pool_kernel<<<GTH, B, 0, stream>>>(entries, rowptr, rowend, dinv,
                                               (const uint4*)hm2f, (const float4*)b2,
                                               batch, psum, pcnt);
    head_kernel<<<(NGRAPHS + B - 1) / B, B, 0, stream>>>(psum, pcnt, fc1W, fc1b, fc2W, fc2b, out);
}

// Round 13
// 211.312 us; speedup vs baseline: 1.0338x; 1.0338x over previous
//
#include <hip/hip_runtime.h>
#include <math.h>

#define NNODES  100000
#define NEDGES  3200000
#define NGRAPHS 1024
#define BNODES  196                              // nodes per bucket
#define NBUCK   ((NNODES + BNODES - 1) / BNODES) // 511
#define SCAP    8192                             // staging capacity per bucket (max ~6.6K)
#define PADCAP  10240                            // padded entries capacity per bucket
#define SLDS    7168                             // binB LDS staging (max bucket ~6.6K)
#define DUMMY   NNODES                           // dummy node with zero feature rows
#define CHUNK   8192                             // edges per binA block (512 thr x 16)
#define NCHUNKS ((NEDGES + CHUNK - 1) / CHUNK)   // 391

typedef int iv4 __attribute__((ext_vector_type(4)));
typedef float fv2 __attribute__((ext_vector_type(2)));

#if defined(__has_builtin)
#if __has_builtin(__builtin_amdgcn_cvt_pk_f32_fp8) && __has_builtin(__builtin_amdgcn_cvt_pk_fp8_f32)
#define HW_FP8 1
#endif
#endif

// ---- bf16x2 pack/unpack (RNE) ----
__device__ __forceinline__ unsigned bf16pair(float a, float b) {
    unsigned ua = __float_as_uint(a), ub = __float_as_uint(b);
    ua += 0x7fffu + ((ua >> 16) & 1u);
    ub += 0x7fffu + ((ub >> 16) & 1u);
    return (ua >> 16) | (ub & 0xffff0000u);
}
__device__ __forceinline__ float bflo(unsigned u) { return __uint_as_float(u << 16); }
__device__ __forceinline__ float bfhi(unsigned u) { return __uint_as_float(u & 0xffff0000u); }

// ---- fp8 e4m3 (OCP) manual fallback ----
__device__ __forceinline__ unsigned fp8_of(float v) {
    unsigned s = (__float_as_uint(v) >> 24) & 0x80u;
    float a = fminf(fabsf(v), 448.f);
    unsigned ub = __float_as_uint(a);
    unsigned lsb = (ub >> 20) & 1u;
    ub += 0x0007FFFFu + lsb;
    int em = (int)(ub >> 20) - (120 << 3);
    if (em < 1) return s;
    if (em > 0x7E) em = 0x7E;
    return s | (unsigned)em;
}
__device__ __forceinline__ float fp8_to_f(unsigned b) {
    unsigned em = b & 0x7Fu;
    unsigned s = (b & 0x80u) << 24;
    float f = __uint_as_float(s | ((em + 0x3C0u) << 20));
    return (em >= 8u) ? f : 0.f;
}
__device__ __forceinline__ unsigned fp8x4_pack(float a, float b, float c, float d) {
    a = fminf(fmaxf(a, -448.f), 448.f);
    b = fminf(fmaxf(b, -448.f), 448.f);
    c = fminf(fmaxf(c, -448.f), 448.f);
    d = fminf(fmaxf(d, -448.f), 448.f);
#ifdef HW_FP8
    int w = __builtin_amdgcn_cvt_pk_fp8_f32(a, b, 0, false);
    w = __builtin_amdgcn_cvt_pk_fp8_f32(c, d, w, true);
    return (unsigned)w;
#else
    return fp8_of(a) | (fp8_of(b) << 8) | (fp8_of(c) << 16) | (fp8_of(d) << 24);
#endif
}
__device__ __forceinline__ fv2 f8lo(unsigned w) {
#ifdef HW_FP8
    return __builtin_amdgcn_cvt_pk_f32_fp8((int)w, false);
#else
    fv2 t; t.x = fp8_to_f(w & 0xFFu); t.y = fp8_to_f((w >> 8) & 0xFFu); return t;
#endif
}
__device__ __forceinline__ fv2 f8hi(unsigned w) {
#ifdef HW_FP8
    return __builtin_amdgcn_cvt_pk_f32_fp8((int)w, true);
#else
    fv2 t; t.x = fp8_to_f((w >> 16) & 0xFFu); t.y = fp8_to_f(w >> 24); return t;
#endif
}

// ---------------- init ----------------

__global__ void zero4_kernel(int4* p, int nvec) {
    int i = blockIdx.x * blockDim.x + threadIdx.x;
    if (i < nvec) p[i] = make_int4(0, 0, 0, 0);
}

// ---------------- binA: LDS-staged bucket sort (512 thr, 8K chunk, no bof: 38KB LDS) ----------------

__global__ void __launch_bounds__(512) binA_kernel(const int* __restrict__ src,
        const int* __restrict__ dst, int* __restrict__ bucketCur, int* __restrict__ stage) {
    __shared__ int lcnt[512];
    __shared__ int boff[512];                     // monotone; boff[511] = cnt (sentinel)
    __shared__ int gbase[512];
    __shared__ int cur[512];
    __shared__ int wtot[8];
    __shared__ int packed[CHUNK];                 // 32 KB
    int tid = threadIdx.x;
    int beg = blockIdx.x * CHUNK;
    int end = beg + CHUNK; if (end > NEDGES) end = NEDGES;
    int cnt = end - beg;

    lcnt[tid] = 0;
    __syncthreads();

    int ent[16];
    int bk[16];
#pragma unroll
    for (int it = 0; it < 4; ++it) {
        int e0 = beg + tid * 4 + it * 2048;
        if (e0 < end) {
            iv4 d4 = __builtin_nontemporal_load((const iv4*)(dst + e0));
            iv4 s4 = __builtin_nontemporal_load((const iv4*)(src + e0));
            int b;
            b = d4.x / BNODES; ent[it*4+0] = s4.x | ((d4.x - b*BNODES) << 17); bk[it*4+0] = b; atomicAdd(&lcnt[b], 1);
            b = d4.y / BNODES; ent[it*4+1] = s4.y | ((d4.y - b*BNODES) << 17); bk[it*4+1] = b; atomicAdd(&lcnt[b], 1);
            b = d4.z / BNODES; ent[it*4+2] = s4.z | ((d4.z - b*BNODES) << 17); bk[it*4+2] = b; atomicAdd(&lcnt[b], 1);
            b = d4.w / BNODES; ent[it*4+3] = s4.w | ((d4.w - b*BNODES) << 17); bk[it*4+3] = b; atomicAdd(&lcnt[b], 1);
        } else {
            bk[it*4+0] = -1; bk[it*4+1] = -1; bk[it*4+2] = -1; bk[it*4+3] = -1;
            ent[it*4+0] = 0; ent[it*4+1] = 0; ent[it*4+2] = 0; ent[it*4+3] = 0;
        }
    }
    __syncthreads();

    // wave-level scan, 1 bucket per thread (512 threads >= NBUCK+1)
    int c = lcnt[tid];
    int lane = tid & 63, wid = tid >> 6;
    int v = c;
#pragma unroll
    for (int o = 1; o < 64; o <<= 1) {
        int t = __shfl_up(v, o, 64);
        if (lane >= o) v += t;
    }
    if (lane == 63) wtot[wid] = v;
    __syncthreads();
    int woff = 0;
#pragma unroll
    for (int w = 0; w < 8; ++w) woff += (w < wid) ? wtot[w] : 0;
    int excl = woff + v - c;
    boff[tid] = excl;
    cur[tid] = excl;
    if (c > 0) gbase[tid] = atomicAdd(&bucketCur[tid], c);
    __syncthreads();

#pragma unroll
    for (int k = 0; k < 16; ++k) {
        int b = bk[k];
        if (b >= 0) {
            int p = atomicAdd(&cur[b], 1);
            packed[p] = ent[k];
        }
    }
    __syncthreads();

    // ordered copy; bucket of position i via binary search over boff (9 steps)
    for (int i = tid; i < cnt; i += 512) {
        int lo = 0, hi = 511;
        while (lo < hi) {
            int mid = (lo + hi + 1) >> 1;
            if (boff[mid] <= i) lo = mid; else hi = mid - 1;
        }
        int b = lo;
        int addr = b * SCAP + gbase[b] + (i - boff[b]);
        stage[addr] = packed[i];
    }
}

// ---------------- binB: 512 thr, vectorized LDS staging + padded CSR + dinv/xs ----------------

__global__ void __launch_bounds__(512) binB_kernel(const int* __restrict__ bucketCur,
                            const int* __restrict__ stage, const float2* __restrict__ x,
                            int* __restrict__ entries, int* __restrict__ rowptr,
                            int* __restrict__ rowend,
                            float* __restrict__ dinv, unsigned* __restrict__ xs,
                            float* __restrict__ psum_z) {
    __shared__ int s[256];
    __shared__ int ncur[256];
    __shared__ float ndinv[256];
    __shared__ int wt[4];
    __shared__ __align__(16) int se[SLDS];       // 28 KB: whole bucket in LDS
    int b = blockIdx.x;
    int cntE = bucketCur[b];
    if (cntE > SLDS) cntE = SLDS;                // safety (never expected: >11 sigma)
    int bbase = b * PADCAP;
    int nlo = b * BNODES;
    int nn = NNODES - nlo; if (nn > BNODES) nn = BNODES;
    int sb = b * SCAP;
    int tid = threadIdx.x;

    // zero psum+pcnt (contiguous 33792 floats) across the 511 blocks
    {
        int zi = b * 68 + tid;
        if (tid < 68 && zi < 33792) psum_z[zi] = 0.f;
    }

    if (tid < 256) s[tid] = 0;
    __syncthreads();
    int nv4 = cntE >> 2;
    for (int q = tid; q < nv4; q += 512) {
        iv4 w4;
        __builtin_memcpy(&w4, stage + sb + 4 * q, 16);
        __builtin_memcpy(se + 4 * q, &w4, 16);
        atomicAdd(&s[(unsigned)w4.x >> 17], 1);
        atomicAdd(&s[(unsigned)w4.y >> 17], 1);
        atomicAdd(&s[(unsigned)w4.z >> 17], 1);
        atomicAdd(&s[(unsigned)w4.w >> 17], 1);
    }
    {
        int e = (nv4 << 2) + tid;
        if (e < cntE) {
            int w = stage[sb + e];
            se[e] = w;
            atomicAdd(&s[(unsigned)w >> 17], 1);
        }
    }
    __syncthreads();

    int lane = tid & 63, wid = tid >> 6;
    int v = 0, p16 = 0, iv = 0;
    if (tid < 256) {
        v = s[tid];
        p16 = (v + 15) & ~15;            // padded row length (multiple of 16)
        iv = p16;
#pragma unroll
        for (int o = 1; o < 64; o <<= 1) {
            int t = __shfl_up(iv, o, 64);
            if (lane >= o) iv += t;
        }
        if (lane == 63) wt[wid] = iv;
    }
    __syncthreads();
    if (tid < 256) {
        int woff = 0;
#pragma unroll
        for (int w2 = 0; w2 < 4; ++w2) woff += (w2 < wid) ? wt[w2] : 0;
        int pexcl = woff + iv - p16;
        ncur[tid] = pexcl;
        if (tid < nn) {
            rowptr[nlo + tid] = bbase + pexcl;
            rowend[nlo + tid] = bbase + pexcl + p16;
            float di = rsqrtf((float)(v + 1));   // +1 self-loop (exact degree)
            dinv[nlo + tid] = di;
            ndinv[tid] = di;
            // pad fill: slots [v, p16) -> DUMMY
            int base = bbase + pexcl;
            for (int j = v; j < p16; ++j) entries[base + j] = DUMMY;
        }
    }
    __syncthreads();
    for (int i = tid; i < nn * 8; i += 512) {
        int node = i >> 3, w = i & 7;
        float2 v2 = x[(size_t)(nlo + node) * 8 + w];
        float di = ndinv[node];
        xs[(nlo + node) * 8 + w] = bf16pair(v2.x * di, v2.y * di);
    }
    if (b == NBUCK - 1) {
        if (tid < 8) xs[NNODES * 8 + tid] = 0u;  // dummy row = 0
    }
    for (int e = tid; e < cntE; e += 512) {
        unsigned w = (unsigned)se[e];
        int dl = (int)(w >> 17);
        int slot = atomicAdd(&ncur[dl], 1);
        entries[bbase + slot] = (int)(w & 0x1FFFFu);
    }
}

// ---------------- fused gather layer 1 + node MLP (pipelined, tail-free) ----------------

__device__ __forceinline__ void acc_bf(unsigned u, fv2& a) {
    fv2 t; t.x = bflo(u); t.y = bfhi(u);
    a += t;
}
#define ACCX4(V) { acc_bf((V).x, acc0); acc_bf((V).y, acc1); acc_bf((V).z, acc2); acc_bf((V).w, acc3); }
#define QRED(a) { a.x += __shfl_xor(a.x, 2); a.y += __shfl_xor(a.y, 2); \
                  a.x += __shfl_xor(a.x, 4); a.y += __shfl_xor(a.y, 4); }

__global__ void __launch_bounds__(256) gatherX_mlp_kernel(const int* __restrict__ entries,
        const int* __restrict__ rowptr, const int* __restrict__ rowend,
        const float* __restrict__ dinv, const uint4* __restrict__ xsv,
        const float* __restrict__ W1, const float* __restrict__ b1,
        const float* __restrict__ W2, unsigned* __restrict__ hm2f) {
    __shared__ __align__(16) float w1s[16 * 64];   // 4 KB
    __shared__ __align__(16) float w2s[64 * 32];   // 8 KB
    __shared__ float bb1[64];
    int tid = threadIdx.x;
    for (int i = tid; i < 16 * 64; i += 256) w1s[i] = W1[i];
    for (int i = tid; i < 64 * 32; i += 256) w2s[i] = W2[i];
    if (tid < 64) bb1[tid] = b1[tid];
    if (blockIdx.x == 0 && tid < 8) hm2f[NNODES * 8 + tid] = 0u;   // dummy row = 0
    __syncthreads();

    int t = blockIdx.x * 256 + tid;
    int n = t >> 3, lane = t & 7;
    int half = lane & 1, quad = lane >> 1;
    int beg = rowptr[n];
    int nb = (rowend[n] - beg) >> 4;         // whole 16-edge blocks only (padded)
    fv2 acc0 = {0.f, 0.f}, acc1 = {0.f, 0.f}, acc2 = {0.f, 0.f}, acc3 = {0.f, 0.f};
    if (quad == 0) {
        uint4 sv = xsv[n * 2 + half];
        ACCX4(sv);
    }

    const int* ep = entries + beg + (quad << 2);
    if (nb > 0) {
        uint4 p0, p1, p2, p3;
        iv4 enx = {0, 0, 0, 0};
        {
            iv4 e; __builtin_memcpy(&e, ep, 16);
            p0 = xsv[e.x * 2 + half]; p1 = xsv[e.y * 2 + half];
            p2 = xsv[e.z * 2 + half]; p3 = xsv[e.w * 2 + half];
            if (nb > 1) __builtin_memcpy(&enx, ep + 16, 16);
        }
        for (int i = 1; i < nb; ++i) {
            uint4 c0 = xsv[enx.x * 2 + half], c1 = xsv[enx.y * 2 + half],
                  c2 = xsv[enx.z * 2 + half], c3 = xsv[enx.w * 2 + half];
            if (i + 1 < nb) __builtin_memcpy(&enx, ep + ((i + 1) << 4), 16);
            ACCX4(p0); ACCX4(p1); ACCX4(p2); ACCX4(p3);
            p0 = c0; p1 = c1; p2 = c2; p3 = c3;
        }
        ACCX4(p0); ACCX4(p1); ACCX4(p2); ACCX4(p3);
    }

    QRED(acc0); QRED(acc1); QRED(acc2); QRED(acc3);

    // all 8 lanes hold the full half-aggregate; scale by dinv
    float di = dinv[n];
    float own[8];
    own[0] = acc0.x * di; own[1] = acc0.y * di; own[2] = acc1.x * di; own[3] = acc1.y * di;
    own[4] = acc2.x * di; own[5] = acc2.y * di; own[6] = acc3.x * di; own[7] = acc3.y * di;
    float oth[8];
#pragma unroll
    for (int i2 = 0; i2 < 8; ++i2) oth[i2] = __shfl_xor(own[i2], 1);
    float a16[16];
#pragma unroll
    for (int k = 0; k < 8; ++k) a16[k]     = (half == 0) ? own[k] : oth[k];
#pragma unroll
    for (int k = 0; k < 8; ++k) a16[8 + k] = (half == 0) ? oth[k] : own[k];

    // phase B: h1[j] for j = lane*8 .. +7 (FMA order preserved)
    float h[8];
    {
        int j0 = lane * 8;
#pragma unroll
        for (int jj = 0; jj < 8; ++jj) h[jj] = bb1[j0 + jj];
#pragma unroll
        for (int k = 0; k < 16; ++k) {
            const float4* wr = (const float4*)(w1s + k * 64 + j0);
            float4 wa = wr[0], wb = wr[1];
            float av = a16[k];
            h[0] += av * wa.x; h[1] += av * wa.y; h[2] += av * wa.z; h[3] += av * wa.w;
            h[4] += av * wb.x; h[5] += av * wb.y; h[6] += av * wb.z; h[7] += av * wb.w;
        }
#pragma unroll
        for (int jj = 0; jj < 8; ++jj) h[jj] = fmaxf(h[jj], 0.f);
    }

    // phase C: h2[j] for j = lane*4 .. +3; h1 via width-8 shuffles, k ascending
    {
        int j0c = lane * 4;
        float c0 = 0.f, c1 = 0.f, c2 = 0.f, c3 = 0.f;
#pragma unroll
        for (int k = 0; k < 64; ++k) {
            float hv = __shfl(h[k & 7], k >> 3, 8);
            float4 w = *(const float4*)(w2s + k * 32 + j0c);
            c0 += hv * w.x; c1 += hv * w.y; c2 += hv * w.z; c3 += hv * w.w;
        }
        float sc = di * 64.f;                       // x64 pre-scale for fp8
        hm2f[n * 8 + lane] = fp8x4_pack(c0 * sc, c1 * sc, c2 * sc, c3 * sc);
    }
}

// ---------------- gather layer 2 + pool: pipelined, tail-free ----------------

#define ACCH4(V) { q0lo += f8lo((V).x); q0hi += f8hi((V).x); \
                   q1lo += f8lo((V).y); q1hi += f8hi((V).y); \
                   q2lo += f8lo((V).z); q2hi += f8hi((V).z); \
                   q3lo += f8lo((V).w); q3hi += f8hi((V).w); }

__global__ void __launch_bounds__(256) gatherH_pool_kernel(const int* __restrict__ entries,
        const int* __restrict__ rowptr, const int* __restrict__ rowend,
        const float* __restrict__ dinv, const uint4* __restrict__ hm4,
        const float4* __restrict__ b2, const int* __restrict__ batch,
        float* __restrict__ psum, float* __restrict__ pcnt) {
    __shared__ float lps[8][32];
    __shared__ float lpc[8];
    int tid = threadIdx.x;
    ((float*)lps)[tid] = 0.f;
    if (tid < 8) lpc[tid] = 0.f;
    __syncthreads();

    int t = blockIdx.x * 256 + tid;
    int n = t >> 3, lane = t & 7;
    int half = lane & 1, quad = lane >> 1;
    int g0 = batch[blockIdx.x * 32];
    int beg = rowptr[n];
    int nb = (rowend[n] - beg) >> 4;
    fv2 q0lo = {0.f,0.f}, q0hi = {0.f,0.f}, q1lo = {0.f,0.f}, q1hi = {0.f,0.f},
        q2lo = {0.f,0.f}, q2hi = {0.f,0.f}, q3lo = {0.f,0.f}, q3hi = {0.f,0.f};
    if (quad == 0) {
        uint4 sv = hm4[n * 2 + half];
        ACCH4(sv);
    }

    const int* ep = entries + beg + (quad << 2);
    if (nb > 0) {
        uint4 p0, p1, p2, p3;
        iv4 enx = {0, 0, 0, 0};
        {
            iv4 e; __builtin_memcpy(&e, ep, 16);
            p0 = hm4[e.x * 2 + half]; p1 = hm4[e.y * 2 + half];
            p2 = hm4[e.z * 2 + half]; p3 = hm4[e.w * 2 + half];
            if (nb > 1) __builtin_memcpy(&enx, ep + 16, 16);
        }
        for (int i = 1; i < nb; ++i) {
            uint4 c0 = hm4[enx.x * 2 + half], c1 = hm4[enx.y * 2 + half],
                  c2 = hm4[enx.z * 2 + half], c3 = hm4[enx.w * 2 + half];
            if (i + 1 < nb) __builtin_memcpy(&enx, ep + ((i + 1) << 4), 16);
            ACCH4(p0); ACCH4(p1); ACCH4(p2); ACCH4(p3);
            p0 = c0; p1 = c1; p2 = c2; p3 = c3;
        }
        ACCH4(p0); ACCH4(p1); ACCH4(p2); ACCH4(p3);
    }

    QRED(q0lo); QRED(q0hi); QRED(q1lo); QRED(q1hi);
    QRED(q2lo); QRED(q2hi); QRED(q3lo); QRED(q3hi);

    if (quad == 0) {
        float sc = dinv[n] * (1.0f / 64.f);         // undo x64 pre-scale
        float4 bv0 = b2[half * 4 + 0], bv1 = b2[half * 4 + 1],
               bv2 = b2[half * 4 + 2], bv3 = b2[half * 4 + 3];
        float vv[16];
        vv[0]  = fmaxf(q0lo.x * sc + bv0.x, 0.f);
        vv[1]  = fmaxf(q0lo.y * sc + bv0.y, 0.f);
        vv[2]  = fmaxf(q0hi.x * sc + bv0.z, 0.f);
        vv[3]  = fmaxf(q0hi.y * sc + bv0.w, 0.f);
        vv[4]  = fmaxf(q1lo.x * sc + bv1.x, 0.f);
        vv[5]  = fmaxf(q1lo.y * sc + bv1.y, 0.f);
        vv[6]  = fmaxf(q1hi.x * sc + bv1.z, 0.f);
        vv[7]  = fmaxf(q1hi.y * sc + bv1.w, 0.f);
        vv[8]  = fmaxf(q2lo.x * sc + bv2.x, 0.f);
        vv[9]  = fmaxf(q2lo.y * sc + bv2.y, 0.f);
        vv[10] = fmaxf(q2hi.x * sc + bv2.z, 0.f);
        vv[11] = fmaxf(q2hi.y * sc + bv2.w, 0.f);
        vv[12] = fmaxf(q3lo.x * sc + bv3.x, 0.f);
        vv[13] = fmaxf(q3lo.y * sc + bv3.y, 0.f);
        vv[14] = fmaxf(q3hi.x * sc + bv3.z, 0.f);
        vv[15] = fmaxf(q3hi.y * sc + bv3.w, 0.f);

        int g = batch[n], gr = g - g0;
        if (gr < 8) {
            float* pg = &lps[gr][half * 16];
#pragma unroll
            for (int k2 = 0; k2 < 16; ++k2) atomicAdd(pg + k2, vv[k2]);
            if (lane == 0) atomicAdd(&lpc[gr], 1.0f);
        } else {
            float* pg = psum + g * 32 + half * 16;
#pragma unroll
            for (int k2 = 0; k2 < 16; ++k2) atomicAdd(pg + k2, vv[k2]);
            if (lane == 0) atomicAdd(&pcnt[g], 1.0f);
        }
    }
    __syncthreads();
    int grf = tid >> 5, f = tid & 31;
    float v = lps[grf][f];
    if (v != 0.f) atomicAdd(&psum[(g0 + grf) * 32 + f], v);
    if (f == 0) {
        float c = lpc[grf];
        if (c != 0.f) atomicAdd(&pcnt[g0 + grf], c);
    }
}

// ---------------- head ----------------

__global__ void head_kernel(const float* __restrict__ psum, const float* __restrict__ pcnt,
                            const float* __restrict__ fc1W, const float* __restrict__ fc1b,
                            const float* __restrict__ fc2W, const float* __restrict__ fc2b,
                            float* __restrict__ out) {
    int g = blockIdx.x * blockDim.x + threadIdx.x;
    if (g >= NGRAPHS) return;
    float inv = 1.0f / fmaxf(pcnt[g], 1.0f);
    float gv[32];
#pragma unroll
    for (int k = 0; k < 32; ++k) gv[k] = psum[g * 32 + k] * inv;
    float o = fc2b[0];
#pragma unroll
    for (int j = 0; j < 16; ++j) {
        float h = fc1b[j];
#pragma unroll
        for (int k = 0; k < 32; ++k) h += gv[k] * fc1W[k * 16 + j];
        h = fmaxf(h, 0.f);
        o += h * fc2W[j];
    }
    out[g] = 1.0f / (1.0f + expf(-o));
}

// ---------------- launch ----------------

extern "C" void kernel_launch(void* const* d_in, const int* in_sizes, int n_in,
                              void* d_out, int out_size, void* d_ws, size_t ws_size,
                              hipStream_t stream) {
    const float* x    = (const float*)d_in[0];
    const int*   ei   = (const int*)d_in[1];
    const int*   batch= (const int*)d_in[2];
    const float* W1   = (const float*)d_in[3];
    const float* b1   = (const float*)d_in[4];
    const float* W2   = (const float*)d_in[5];
    const float* b2   = (const float*)d_in[6];
    const float* fc1W = (const float*)d_in[7];
    const float* fc1b = (const float*)d_in[8];
    const float* fc2W = (const float*)d_in[9];
    const float* fc2b = (const float*)d_in[10];
    float* out = (float*)d_out;

    const int* src = ei;
    const int* dst = ei + NEDGES;

    char* wsb = (char*)d_ws;
    int*      bucketCur = (int*)wsb;                 // 2048 B  (zeroed by zero4)
    float*    psum      = (float*)(wsb + 2048);      // 131072  (zeroed in binB)
    float*    pcnt      = (float*)(wsb + 133120);    // 4096    (zeroed in binB)
    float*    dinv      = (float*)(wsb + 137216);    // 400000
    int*      rowptr    = (int*)(wsb + 537216);      // 400000
    int*      rowend    = (int*)(wsb + 937216);      // 400000
    int*      stage     = (int*)(wsb + 1337216);     // 16.7 MB (511*8192*4)
    int*      entries   = (int*)(wsb + 18081664);    // 20.9 MB (511*10240*4, padded CSR)
    unsigned* xs        = (unsigned*)(wsb + 39012224);   // 3.2 MB + dummy row (bf16x2)
    unsigned* hm2f      = (unsigned*)(wsb + 42212256);   // 3.2 MB + dummy row (fp8)

    const int B = 256;
    zero4_kernel<<<1, 128, 0, stream>>>((int4*)wsb, 128);   // bucketCur only

    binA_kernel<<<NCHUNKS, 512, 0, stream>>>(src, dst, bucketCur, stage);
    binB_kernel<<<NBUCK, 512, 0, stream>>>(bucketCur, stage, (const float2*)x,
                                           entries, rowptr, rowend, dinv, xs, psum);

    const int GTH = NNODES * 8 / B;                  // 3125
    gatherX_mlp_kernel<<<GTH, B, 0, stream>>>(entries, rowptr, rowend, dinv,
                                              (const uint4*)xs, W1, b1, W2, hm2f);
    gatherH_pool_kernel<<<GTH, B, 0, stream>>>(entries, rowptr, rowend, dinv,
                                               (const uint4*)hm2f, (const float4*)b2,
                                               batch, psum, pcnt);
    head_kernel<<<(NGRAPHS + B - 1) / B, B, 0, stream>>>(psum, pcnt, fc1W, fc1b, fc2W, fc2b, out);
}

// Round 14
// 207.150 us; speedup vs baseline: 1.0546x; 1.0201x over previous
//
#include <hip/hip_runtime.h>
#include <math.h>

#define NNODES  100000
#define NEDGES  3200000
#define NGRAPHS 1024
#define BNODES  196                              // nodes per bucket
#define NBUCK   ((NNODES + BNODES - 1) / BNODES) // 511
#define SCAP    8192                             // staging capacity per bucket (max ~6.6K)
#define PADCAP  10240                            // padded entries capacity per bucket
#define SLDS    7168                             // binB LDS staging (max bucket ~6.6K)
#define DUMMY   NNODES                           // dummy node with zero feature rows
#define CHUNK   8192                             // edges per binA block (512 thr x 16)
#define NCHUNKS ((NEDGES + CHUNK - 1) / CHUNK)   // 391

typedef int iv4 __attribute__((ext_vector_type(4)));
typedef float fv2 __attribute__((ext_vector_type(2)));

#if defined(__has_builtin)
#if __has_builtin(__builtin_amdgcn_cvt_pk_f32_fp8) && __has_builtin(__builtin_amdgcn_cvt_pk_fp8_f32)
#define HW_FP8 1
#endif
#endif

// ---- bf16x2 pack/unpack (RNE) ----
__device__ __forceinline__ unsigned bf16pair(float a, float b) {
    unsigned ua = __float_as_uint(a), ub = __float_as_uint(b);
    ua += 0x7fffu + ((ua >> 16) & 1u);
    ub += 0x7fffu + ((ub >> 16) & 1u);
    return (ua >> 16) | (ub & 0xffff0000u);
}
__device__ __forceinline__ float bflo(unsigned u) { return __uint_as_float(u << 16); }
__device__ __forceinline__ float bfhi(unsigned u) { return __uint_as_float(u & 0xffff0000u); }

// ---- fp8 e4m3 (OCP) manual fallback ----
__device__ __forceinline__ unsigned fp8_of(float v) {
    unsigned s = (__float_as_uint(v) >> 24) & 0x80u;
    float a = fminf(fabsf(v), 448.f);
    unsigned ub = __float_as_uint(a);
    unsigned lsb = (ub >> 20) & 1u;
    ub += 0x0007FFFFu + lsb;
    int em = (int)(ub >> 20) - (120 << 3);
    if (em < 1) return s;
    if (em > 0x7E) em = 0x7E;
    return s | (unsigned)em;
}
__device__ __forceinline__ float fp8_to_f(unsigned b) {
    unsigned em = b & 0x7Fu;
    unsigned s = (b & 0x80u) << 24;
    float f = __uint_as_float(s | ((em + 0x3C0u) << 20));
    return (em >= 8u) ? f : 0.f;
}
__device__ __forceinline__ unsigned fp8x4_pack(float a, float b, float c, float d) {
    a = fminf(fmaxf(a, -448.f), 448.f);
    b = fminf(fmaxf(b, -448.f), 448.f);
    c = fminf(fmaxf(c, -448.f), 448.f);
    d = fminf(fmaxf(d, -448.f), 448.f);
#ifdef HW_FP8
    int w = __builtin_amdgcn_cvt_pk_fp8_f32(a, b, 0, false);
    w = __builtin_amdgcn_cvt_pk_fp8_f32(c, d, w, true);
    return (unsigned)w;
#else
    return fp8_of(a) | (fp8_of(b) << 8) | (fp8_of(c) << 16) | (fp8_of(d) << 24);
#endif
}
__device__ __forceinline__ fv2 f8lo(unsigned w) {
#ifdef HW_FP8
    return __builtin_amdgcn_cvt_pk_f32_fp8((int)w, false);
#else
    fv2 t; t.x = fp8_to_f(w & 0xFFu); t.y = fp8_to_f((w >> 8) & 0xFFu); return t;
#endif
}
__device__ __forceinline__ fv2 f8hi(unsigned w) {
#ifdef HW_FP8
    return __builtin_amdgcn_cvt_pk_f32_fp8((int)w, true);
#else
    fv2 t; t.x = fp8_to_f((w >> 16) & 0xFFu); t.y = fp8_to_f(w >> 24); return t;
#endif
}

// ---------------- init ----------------

__global__ void zero4_kernel(int4* p, int nvec) {
    int i = blockIdx.x * blockDim.x + threadIdx.x;
    if (i < nvec) p[i] = make_int4(0, 0, 0, 0);
}

// ---------------- binA: LDS-staged bucket sort (512 thr, 8K chunk, no bof: 38KB LDS) ----------------

__global__ void __launch_bounds__(512) binA_kernel(const int* __restrict__ src,
        const int* __restrict__ dst, int* __restrict__ bucketCur, int* __restrict__ stage) {
    __shared__ int lcnt[512];
    __shared__ int boff[512];                     // monotone; boff[511] = cnt (sentinel)
    __shared__ int gbase[512];
    __shared__ int cur[512];
    __shared__ int wtot[8];
    __shared__ int packed[CHUNK];                 // 32 KB
    int tid = threadIdx.x;
    int beg = blockIdx.x * CHUNK;
    int end = beg + CHUNK; if (end > NEDGES) end = NEDGES;
    int cnt = end - beg;

    lcnt[tid] = 0;
    __syncthreads();

    int ent[16];
    int bk[16];
#pragma unroll
    for (int it = 0; it < 4; ++it) {
        int e0 = beg + tid * 4 + it * 2048;
        if (e0 < end) {
            iv4 d4 = __builtin_nontemporal_load((const iv4*)(dst + e0));
            iv4 s4 = __builtin_nontemporal_load((const iv4*)(src + e0));
            int b;
            b = d4.x / BNODES; ent[it*4+0] = s4.x | ((d4.x - b*BNODES) << 17); bk[it*4+0] = b; atomicAdd(&lcnt[b], 1);
            b = d4.y / BNODES; ent[it*4+1] = s4.y | ((d4.y - b*BNODES) << 17); bk[it*4+1] = b; atomicAdd(&lcnt[b], 1);
            b = d4.z / BNODES; ent[it*4+2] = s4.z | ((d4.z - b*BNODES) << 17); bk[it*4+2] = b; atomicAdd(&lcnt[b], 1);
            b = d4.w / BNODES; ent[it*4+3] = s4.w | ((d4.w - b*BNODES) << 17); bk[it*4+3] = b; atomicAdd(&lcnt[b], 1);
        } else {
            bk[it*4+0] = -1; bk[it*4+1] = -1; bk[it*4+2] = -1; bk[it*4+3] = -1;
            ent[it*4+0] = 0; ent[it*4+1] = 0; ent[it*4+2] = 0; ent[it*4+3] = 0;
        }
    }
    __syncthreads();

    // wave-level scan, 1 bucket per thread (512 threads >= NBUCK+1)
    int c = lcnt[tid];
    int lane = tid & 63, wid = tid >> 6;
    int v = c;
#pragma unroll
    for (int o = 1; o < 64; o <<= 1) {
        int t = __shfl_up(v, o, 64);
        if (lane >= o) v += t;
    }
    if (lane == 63) wtot[wid] = v;
    __syncthreads();
    int woff = 0;
#pragma unroll
    for (int w = 0; w < 8; ++w) woff += (w < wid) ? wtot[w] : 0;
    int excl = woff + v - c;
    boff[tid] = excl;
    cur[tid] = excl;
    if (c > 0) gbase[tid] = atomicAdd(&bucketCur[tid], c);
    __syncthreads();

#pragma unroll
    for (int k = 0; k < 16; ++k) {
        int b = bk[k];
        if (b >= 0) {
            int p = atomicAdd(&cur[b], 1);
            packed[p] = ent[k];
        }
    }
    __syncthreads();

    // ordered copy; bucket of position i via binary search over boff (9 steps)
    for (int i = tid; i < cnt; i += 512) {
        int lo = 0, hi = 511;
        while (lo < hi) {
            int mid = (lo + hi + 1) >> 1;
            if (boff[mid] <= i) lo = mid; else hi = mid - 1;
        }
        int b = lo;
        int addr = b * SCAP + gbase[b] + (i - boff[b]);
        stage[addr] = packed[i];
    }
}

// ---------------- binB: 512 thr, single-atomic-pass (slot reuse) + padded CSR + dinv/xs ----------------

__global__ void __launch_bounds__(512) binB_kernel(const int* __restrict__ bucketCur,
                            const int* __restrict__ stage, const float2* __restrict__ x,
                            int* __restrict__ entries, int* __restrict__ rowptr,
                            int* __restrict__ rowend,
                            float* __restrict__ dinv, unsigned* __restrict__ xs,
                            float* __restrict__ psum_z) {
    __shared__ int s[256];
    __shared__ int nbase[256];
    __shared__ float ndinv[256];
    __shared__ int wt[4];
    __shared__ __align__(16) int se[SLDS];            // 28 KB: whole bucket in LDS
    __shared__ unsigned char slds[SLDS];              // 7 KB: per-edge within-row slot
    int b = blockIdx.x;
    int cntE = bucketCur[b];
    if (cntE > SLDS) cntE = SLDS;                // safety (never expected: >11 sigma)
    int bbase = b * PADCAP;
    int nlo = b * BNODES;
    int nn = NNODES - nlo; if (nn > BNODES) nn = BNODES;
    int sb = b * SCAP;
    int tid = threadIdx.x;

    // zero psum+pcnt (contiguous 33792 floats) across the 511 blocks
    {
        int zi = b * 68 + tid;
        if (tid < 68 && zi < 33792) psum_z[zi] = 0.f;
    }

    if (tid < 256) s[tid] = 0;
    __syncthreads();
    // single atomic pass: histogram AND slot assignment (atomic return = slot)
    int nv4 = cntE >> 2;
    for (int q = tid; q < nv4; q += 512) {
        iv4 w4;
        __builtin_memcpy(&w4, stage + sb + 4 * q, 16);
        __builtin_memcpy(se + 4 * q, &w4, 16);
        slds[4 * q + 0] = (unsigned char)atomicAdd(&s[(unsigned)w4.x >> 17], 1);
        slds[4 * q + 1] = (unsigned char)atomicAdd(&s[(unsigned)w4.y >> 17], 1);
        slds[4 * q + 2] = (unsigned char)atomicAdd(&s[(unsigned)w4.z >> 17], 1);
        slds[4 * q + 3] = (unsigned char)atomicAdd(&s[(unsigned)w4.w >> 17], 1);
    }
    {
        int e = (nv4 << 2) + tid;
        if (e < cntE) {
            int w = stage[sb + e];
            se[e] = w;
            slds[e] = (unsigned char)atomicAdd(&s[(unsigned)w >> 17], 1);
        }
    }
    __syncthreads();

    int lane = tid & 63, wid = tid >> 6;
    int v = 0, p16 = 0, iv = 0;
    if (tid < 256) {
        v = s[tid];
        p16 = (v + 15) & ~15;            // padded row length (multiple of 16)
        iv = p16;
#pragma unroll
        for (int o = 1; o < 64; o <<= 1) {
            int t = __shfl_up(iv, o, 64);
            if (lane >= o) iv += t;
        }
        if (lane == 63) wt[wid] = iv;
    }
    __syncthreads();
    if (tid < 256) {
        int woff = 0;
#pragma unroll
        for (int w2 = 0; w2 < 4; ++w2) woff += (w2 < wid) ? wt[w2] : 0;
        int pexcl = woff + iv - p16;
        nbase[tid] = pexcl;
        if (tid < nn) {
            rowptr[nlo + tid] = bbase + pexcl;
            rowend[nlo + tid] = bbase + pexcl + p16;
            float di = rsqrtf((float)(v + 1));   // +1 self-loop (exact degree)
            dinv[nlo + tid] = di;
            ndinv[tid] = di;
            // pad fill: slots [v, p16) -> DUMMY
            int base = bbase + pexcl;
            for (int j = v; j < p16; ++j) entries[base + j] = DUMMY;
        }
    }
    __syncthreads();
    for (int i = tid; i < nn * 8; i += 512) {
        int node = i >> 3, w = i & 7;
        float2 v2 = x[(size_t)(nlo + node) * 8 + w];
        float di = ndinv[node];
        xs[(nlo + node) * 8 + w] = bf16pair(v2.x * di, v2.y * di);
    }
    if (b == NBUCK - 1) {
        if (tid < 8) xs[NNODES * 8 + tid] = 0u;  // dummy row = 0
    }
    // atomic-free scatter: position = nbase[dl] + pre-assigned slot
    for (int e = tid; e < cntE; e += 512) {
        unsigned w = (unsigned)se[e];
        int dl = (int)(w >> 17);
        int slot = (int)slds[e];
        entries[bbase + nbase[dl] + slot] = (int)(w & 0x1FFFFu);
    }
}

// ---------------- fused gather layer 1 + node MLP (pipelined, tail-free) ----------------

__device__ __forceinline__ void acc_bf(unsigned u, fv2& a) {
    fv2 t; t.x = bflo(u); t.y = bfhi(u);
    a += t;
}
#define ACCX4(V) { acc_bf((V).x, acc0); acc_bf((V).y, acc1); acc_bf((V).z, acc2); acc_bf((V).w, acc3); }
#define QRED(a) { a.x += __shfl_xor(a.x, 2); a.y += __shfl_xor(a.y, 2); \
                  a.x += __shfl_xor(a.x, 4); a.y += __shfl_xor(a.y, 4); }

__global__ void __launch_bounds__(256) gatherX_mlp_kernel(const int* __restrict__ entries,
        const int* __restrict__ rowptr, const int* __restrict__ rowend,
        const float* __restrict__ dinv, const uint4* __restrict__ xsv,
        const float* __restrict__ W1, const float* __restrict__ b1,
        const float* __restrict__ W2, unsigned* __restrict__ hm2f) {
    __shared__ __align__(16) float w1s[16 * 64];   // 4 KB
    __shared__ __align__(16) float w2s[64 * 32];   // 8 KB
    __shared__ float bb1[64];
    int tid = threadIdx.x;
    for (int i = tid; i < 16 * 64; i += 256) w1s[i] = W1[i];
    for (int i = tid; i < 64 * 32; i += 256) w2s[i] = W2[i];
    if (tid < 64) bb1[tid] = b1[tid];
    if (blockIdx.x == 0 && tid < 8) hm2f[NNODES * 8 + tid] = 0u;   // dummy row = 0
    __syncthreads();

    int t = blockIdx.x * 256 + tid;
    int n = t >> 3, lane = t & 7;
    int half = lane & 1, quad = lane >> 1;
    int beg = rowptr[n];
    int nb = (rowend[n] - beg) >> 4;         // whole 16-edge blocks only (padded)
    fv2 acc0 = {0.f, 0.f}, acc1 = {0.f, 0.f}, acc2 = {0.f, 0.f}, acc3 = {0.f, 0.f};
    if (quad == 0) {
        uint4 sv = xsv[n * 2 + half];
        ACCX4(sv);
    }

    const int* ep = entries + beg + (quad << 2);
    if (nb > 0) {
        uint4 p0, p1, p2, p3;
        iv4 enx = {0, 0, 0, 0};
        {
            iv4 e; __builtin_memcpy(&e, ep, 16);
            p0 = xsv[e.x * 2 + half]; p1 = xsv[e.y * 2 + half];
            p2 = xsv[e.z * 2 + half]; p3 = xsv[e.w * 2 + half];
            if (nb > 1) __builtin_memcpy(&enx, ep + 16, 16);
        }
        for (int i = 1; i < nb; ++i) {
            uint4 c0 = xsv[enx.x * 2 + half], c1 = xsv[enx.y * 2 + half],
                  c2 = xsv[enx.z * 2 + half], c3 = xsv[enx.w * 2 + half];
            if (i + 1 < nb) __builtin_memcpy(&enx, ep + ((i + 1) << 4), 16);
            ACCX4(p0); ACCX4(p1); ACCX4(p2); ACCX4(p3);
            p0 = c0; p1 = c1; p2 = c2; p3 = c3;
        }
        ACCX4(p0); ACCX4(p1); ACCX4(p2); ACCX4(p3);
    }

    QRED(acc0); QRED(acc1); QRED(acc2); QRED(acc3);

    // all 8 lanes hold the full half-aggregate; scale by dinv
    float di = dinv[n];
    float own[8];
    own[0] = acc0.x * di; own[1] = acc0.y * di; own[2] = acc1.x * di; own[3] = acc1.y * di;
    own[4] = acc2.x * di; own[5] = acc2.y * di; own[6] = acc3.x * di; own[7] = acc3.y * di;
    float oth[8];
#pragma unroll
    for (int i2 = 0; i2 < 8; ++i2) oth[i2] = __shfl_xor(own[i2], 1);
    float a16[16];
#pragma unroll
    for (int k = 0; k < 8; ++k) a16[k]     = (half == 0) ? own[k] : oth[k];
#pragma unroll
    for (int k = 0; k < 8; ++k) a16[8 + k] = (half == 0) ? oth[k] : own[k];

    // phase B: h1[j] for j = lane*8 .. +7 (FMA order preserved)
    float h[8];
    {
        int j0 = lane * 8;
#pragma unroll
        for (int jj = 0; jj < 8; ++jj) h[jj] = bb1[j0 + jj];
#pragma unroll
        for (int k = 0; k < 16; ++k) {
            const float4* wr = (const float4*)(w1s + k * 64 + j0);
            float4 wa = wr[0], wb = wr[1];
            float av = a16[k];
            h[0] += av * wa.x; h[1] += av * wa.y; h[2] += av * wa.z; h[3] += av * wa.w;
            h[4] += av * wb.x; h[5] += av * wb.y; h[6] += av * wb.z; h[7] += av * wb.w;
        }
#pragma unroll
        for (int jj = 0; jj < 8; ++jj) h[jj] = fmaxf(h[jj], 0.f);
    }

    // phase C: h2[j] for j = lane*4 .. +3; h1 via width-8 shuffles, k ascending
    {
        int j0c = lane * 4;
        float c0 = 0.f, c1 = 0.f, c2 = 0.f, c3 = 0.f;
#pragma unroll
        for (int k = 0; k < 64; ++k) {
            float hv = __shfl(h[k & 7], k >> 3, 8);
            float4 w = *(const float4*)(w2s + k * 32 + j0c);
            c0 += hv * w.x; c1 += hv * w.y; c2 += hv * w.z; c3 += hv * w.w;
        }
        float sc = di * 64.f;                       // x64 pre-scale for fp8
        hm2f[n * 8 + lane] = fp8x4_pack(c0 * sc, c1 * sc, c2 * sc, c3 * sc);
    }
}

// ---------------- gather layer 2 + pool: pipelined, tail-free ----------------

#define ACCH4(V) { q0lo += f8lo((V).x); q0hi += f8hi((V).x); \
                   q1lo += f8lo((V).y); q1hi += f8hi((V).y); \
                   q2lo += f8lo((V).z); q2hi += f8hi((V).z); \
                   q3lo += f8lo((V).w); q3hi += f8hi((V).w); }

__global__ void __launch_bounds__(256) gatherH_pool_kernel(const int* __restrict__ entries,
        const int* __restrict__ rowptr, const int* __restrict__ rowend,
        const float* __restrict__ dinv, const uint4* __restrict__ hm4,
        const float4* __restrict__ b2, const int* __restrict__ batch,
        float* __restrict__ psum, float* __restrict__ pcnt) {
    __shared__ float lps[8][32];
    __shared__ float lpc[8];
    int tid = threadIdx.x;
    ((float*)lps)[tid] = 0.f;
    if (tid < 8) lpc[tid] = 0.f;
    __syncthreads();

    int t = blockIdx.x * 256 + tid;
    int n = t >> 3, lane = t & 7;
    int half = lane & 1, quad = lane >> 1;
    int g0 = batch[blockIdx.x * 32];
    int beg = rowptr[n];
    int nb = (rowend[n] - beg) >> 4;
    fv2 q0lo = {0.f,0.f}, q0hi = {0.f,0.f}, q1lo = {0.f,0.f}, q1hi = {0.f,0.f},
        q2lo = {0.f,0.f}, q2hi = {0.f,0.f}, q3lo = {0.f,0.f}, q3hi = {0.f,0.f};
    if (quad == 0) {
        uint4 sv = hm4[n * 2 + half];
        ACCH4(sv);
    }

    const int* ep = entries + beg + (quad << 2);
    if (nb > 0) {
        uint4 p0, p1, p2, p3;
        iv4 enx = {0, 0, 0, 0};
        {
            iv4 e; __builtin_memcpy(&e, ep, 16);
            p0 = hm4[e.x * 2 + half]; p1 = hm4[e.y * 2 + half];
            p2 = hm4[e.z * 2 + half]; p3 = hm4[e.w * 2 + half];
            if (nb > 1) __builtin_memcpy(&enx, ep + 16, 16);
        }
        for (int i = 1; i < nb; ++i) {
            uint4 c0 = hm4[enx.x * 2 + half], c1 = hm4[enx.y * 2 + half],
                  c2 = hm4[enx.z * 2 + half], c3 = hm4[enx.w * 2 + half];
            if (i + 1 < nb) __builtin_memcpy(&enx, ep + ((i + 1) << 4), 16);
            ACCH4(p0); ACCH4(p1); ACCH4(p2); ACCH4(p3);
            p0 = c0; p1 = c1; p2 = c2; p3 = c3;
        }
        ACCH4(p0); ACCH4(p1); ACCH4(p2); ACCH4(p3);
    }

    QRED(q0lo); QRED(q0hi); QRED(q1lo); QRED(q1hi);
    QRED(q2lo); QRED(q2hi); QRED(q3lo); QRED(q3hi);

    if (quad == 0) {
        float sc = dinv[n] * (1.0f / 64.f);         // undo x64 pre-scale
        float4 bv0 = b2[half * 4 + 0], bv1 = b2[half * 4 + 1],
               bv2 = b2[half * 4 + 2], bv3 = b2[half * 4 + 3];
        float vv[16];
        vv[0]  = fmaxf(q0lo.x * sc + bv0.x, 0.f);
        vv[1]  = fmaxf(q0lo.y * sc + bv0.y, 0.f);
        vv[2]  = fmaxf(q0hi.x * sc + bv0.z, 0.f);
        vv[3]  = fmaxf(q0hi.y * sc + bv0.w, 0.f);
        vv[4]  = fmaxf(q1lo.x * sc + bv1.x, 0.f);
        vv[5]  = fmaxf(q1lo.y * sc + bv1.y, 0.f);
        vv[6]  = fmaxf(q1hi.x * sc + bv1.z, 0.f);
        vv[7]  = fmaxf(q1hi.y * sc + bv1.w, 0.f);
        vv[8]  = fmaxf(q2lo.x * sc + bv2.x, 0.f);
        vv[9]  = fmaxf(q2lo.y * sc + bv2.y, 0.f);
        vv[10] = fmaxf(q2hi.x * sc + bv2.z, 0.f);
        vv[11] = fmaxf(q2hi.y * sc + bv2.w, 0.f);
        vv[12] = fmaxf(q3lo.x * sc + bv3.x, 0.f);
        vv[13] = fmaxf(q3lo.y * sc + bv3.y, 0.f);
        vv[14] = fmaxf(q3hi.x * sc + bv3.z, 0.f);
        vv[15] = fmaxf(q3hi.y * sc + bv3.w, 0.f);

        int g = batch[n], gr = g - g0;
        if (gr < 8) {
            float* pg = &lps[gr][half * 16];
#pragma unroll
            for (int k2 = 0; k2 < 16; ++k2) atomicAdd(pg + k2, vv[k2]);
            if (lane == 0) atomicAdd(&lpc[gr], 1.0f);
        } else {
            float* pg = psum + g * 32 + half * 16;
#pragma unroll
            for (int k2 = 0; k2 < 16; ++k2) atomicAdd(pg + k2, vv[k2]);
            if (lane == 0) atomicAdd(&pcnt[g], 1.0f);
        }
    }
    __syncthreads();
    int grf = tid >> 5, f = tid & 31;
    float v = lps[grf][f];
    if (v != 0.f) atomicAdd(&psum[(g0 + grf) * 32 + f], v);
    if (f == 0) {
        float c = lpc[grf];
        if (c != 0.f) atomicAdd(&pcnt[g0 + grf], c);
    }
}

// ---------------- head ----------------

__global__ void head_kernel(const float* __restrict__ psum, const float* __restrict__ pcnt,
                            const float* __restrict__ fc1W, const float* __restrict__ fc1b,
                            const float* __restrict__ fc2W, const float* __restrict__ fc2b,
                            float* __restrict__ out) {
    int g = blockIdx.x * blockDim.x + threadIdx.x;
    if (g >= NGRAPHS) return;
    float inv = 1.0f / fmaxf(pcnt[g], 1.0f);
    float gv[32];
#pragma unroll
    for (int k = 0; k < 32; ++k) gv[k] = psum[g * 32 + k] * inv;
    float o = fc2b[0];
#pragma unroll
    for (int j = 0; j < 16; ++j) {
        float h = fc1b[j];
#pragma unroll
        for (int k = 0; k < 32; ++k) h += gv[k] * fc1W[k * 16 + j];
        h = fmaxf(h, 0.f);
        o += h * fc2W[j];
    }
    out[g] = 1.0f / (1.0f + expf(-o));
}

// ---------------- launch ----------------

extern "C" void kernel_launch(void* const* d_in, const int* in_sizes, int n_in,
                              void* d_out, int out_size, void* d_ws, size_t ws_size,
                              hipStream_t stream) {
    const float* x    = (const float*)d_in[0];
    const int*   ei   = (const int*)d_in[1];
    const int*   batch= (const int*)d_in[2];
    const float* W1   = (const float*)d_in[3];
    const float* b1   = (const float*)d_in[4];
    const float* W2   = (const float*)d_in[5];
    const float* b2   = (const float*)d_in[6];
    const float* fc1W = (const float*)d_in[7];
    const float* fc1b = (const float*)d_in[8];
    const float* fc2W = (const float*)d_in[9];
    const float* fc2b = (const float*)d_in[10];
    float* out = (float*)d_out;

    const int* src = ei;
    const int* dst = ei + NEDGES;

    char* wsb = (char*)d_ws;
    int*      bucketCur = (int*)wsb;                 // 2048 B  (zeroed by zero4)
    float*    psum      = (float*)(wsb + 2048);      // 131072  (zeroed in binB)
    float*    pcnt      = (float*)(wsb + 133120);    // 4096    (zeroed in binB)
    float*    dinv      = (float*)(wsb + 137216);    // 400000
    int*      rowptr    = (int*)(wsb + 537216);      // 400000
    int*      rowend    = (int*)(wsb + 937216);      // 400000
    int*      stage     = (int*)(wsb + 1337216);     // 16.7 MB (511*8192*4)
    int*      entries   = (int*)(wsb + 18081664);    // 20.9 MB (511*10240*4, padded CSR)
    unsigned* xs        = (unsigned*)(wsb + 39012224);   // 3.2 MB + dummy row (bf16x2)
    unsigned* hm2f      = (unsigned*)(wsb + 42212256);   // 3.2 MB + dummy row (fp8)

    const int B = 256;
    zero4_kernel<<<1, 128, 0, stream>>>((int4*)wsb, 128);   // bucketCur only

    binA_kernel<<<NCHUNKS, 512, 0, stream>>>(src, dst, bucketCur, stage);
    binB_kernel<<<NBUCK, 512, 0, stream>>>(bucketCur, stage, (const float2*)x,
                                           entries, rowptr, rowend, dinv, xs, psum);

    const int GTH = NNODES * 8 / B;                  // 3125
    gatherX_mlp_kernel<<<GTH, B, 0, stream>>>(entries, rowptr, rowend, dinv,
                                              (const uint4*)xs, W1, b1, W2, hm2f);
    gatherH_pool_kernel<<<GTH, B, 0, stream>>>(entries, rowptr, rowend, dinv,
                                               (const uint4*)hm2f, (const float4*)b2,
                                               batch, psum, pcnt);
    head_kernel<<<(NGRAPHS + B - 1) / B, B, 0, stream>>>(psum, pcnt, fc1W, fc1b, fc2W, fc2b, out);
}